// Round 1
// baseline (371242.773 us; speedup 1.0000x reference)
//
#include <hip/hip_runtime.h>
#include <hip/hip_bf16.h>

#define T_STEPS 32768
#define DIM     1024    // D == U == 1024
#define NGATE   4096    // 4*U
#define GWG     128     // persistent workgroups in scan
#define UPW     8       // units per WG (1024/128)

typedef __attribute__((ext_vector_type(8))) short  short8;
typedef __attribute__((ext_vector_type(4))) float  floatx4;

static __device__ __forceinline__ unsigned short f2bf(float f) {
    union { __hip_bfloat16 h; unsigned short u; } cv;
    cv.h = __float2bfloat16(f);
    return cv.u;
}
static __device__ __forceinline__ float bf2f(unsigned short u) {
    union { float f; unsigned int i; } cv;
    cv.i = ((unsigned int)u) << 16;
    return cv.f;
}
static __device__ __forceinline__ float fast_sigmoid(float x) {
    float e = __builtin_amdgcn_exp2f(x * -1.442695041f);   // exp(-x)
    return __builtin_amdgcn_rcpf(1.f + e);
}
static __device__ __forceinline__ float fast_tanh(float x) {
    float e = __builtin_amdgcn_exp2f(x * -2.885390082f);   // exp(-2x)
    return __builtin_amdgcn_rcpf(1.f + e) * 2.f - 1.f;
}

// ---------------- conversion kernels ----------------

// x fp32 [T*D] -> bf16, 4 elems/thread
__global__ void conv_x_kernel(const float* __restrict__ x,
                              unsigned short* __restrict__ xb, long n4) {
    long i = (long)blockIdx.x * blockDim.x + threadIdx.x;
    if (i >= n4) return;
    floatx4 v = ((const floatx4*)x)[i];
    unsigned long long p =  (unsigned long long)f2bf(v[0])
                         | ((unsigned long long)f2bf(v[1]) << 16)
                         | ((unsigned long long)f2bf(v[2]) << 32)
                         | ((unsigned long long)f2bf(v[3]) << 48);
    ((unsigned long long*)xb)[i] = p;
}

// kernel fp32 [K=1024][4096] -> Wbt bf16 [N=4096][K=1024], with gate/unit remap:
// n(c) groups columns as [wg][gate][unit_in_wg] so each scan WG reads 32 contiguous zx cols.
__global__ void conv_w_kernel(const float* __restrict__ kern,
                              unsigned short* __restrict__ wbt) {
    int idx = blockIdx.x * 256 + threadIdx.x;    // 4096 blocks -> 1M threads
    int kb  = idx >> 12;                         // k block of 4 (0..255)
    int c   = idx & 4095;                        // original column
    int n = ((c & 1023) >> 3) * 32 + (c >> 10) * 8 + (c & 7);
    unsigned long long p = 0;
#pragma unroll
    for (int i = 0; i < 4; ++i) {
        float f = kern[(size_t)(kb * 4 + i) * NGATE + c];
        p |= (unsigned long long)f2bf(f) << (16 * i);
    }
    ((unsigned long long*)(wbt + (size_t)n * DIM))[kb] = p;
}

__global__ void init_kernel(float* hbuf, float* cst, int* flags) {
    int t = threadIdx.x;
    for (int i = t; i < 2048; i += 256) hbuf[i] = 0.f;
    for (int i = t; i < 1024; i += 256) cst[i] = 0.f;
    if (t < GWG) flags[t] = 0;
}

// ---------------- zx GEMM: zxb[t][n'] = sum_k xb[t][k] * Wbt[n'][k]  (bf16 MFMA) ---------

__global__ __launch_bounds__(256) void gemm_kernel(
        const unsigned short* __restrict__ xb,
        const unsigned short* __restrict__ wbt,
        unsigned short* __restrict__ zxb, int t0) {
    __shared__ unsigned short As[64 * 40];   // 64 rows x 32 k, stride 40 (pad)
    __shared__ unsigned short Bs[64 * 40];
    const int tid = threadIdx.x;
    const int w = tid >> 6, l = tid & 63;
    const int mBase = t0 + blockIdx.x * 64;  // global t row
    const int nBase = blockIdx.y * 64;
    const int r  = tid >> 2;                 // staging row 0..63
    const int kc = (tid & 3) * 8;            // staging k offset
    const int lm = l & 15, kq = l >> 4;

    floatx4 acc[4];
#pragma unroll
    for (int i = 0; i < 4; ++i) acc[i] = (floatx4){0.f, 0.f, 0.f, 0.f};

    for (int kt = 0; kt < DIM; kt += 32) {
        *(uint4*)&As[r * 40 + kc] = *(const uint4*)&xb [(size_t)(mBase + r) * DIM + kt + kc];
        *(uint4*)&Bs[r * 40 + kc] = *(const uint4*)&wbt[(size_t)(nBase + r) * DIM + kt + kc];
        __syncthreads();
        short8 a = *(const short8*)&As[(w * 16 + lm) * 40 + kq * 8];
#pragma unroll
        for (int i = 0; i < 4; ++i) {
            short8 b = *(const short8*)&Bs[(i * 16 + lm) * 40 + kq * 8];
            acc[i] = __builtin_amdgcn_mfma_f32_16x16x32_bf16(a, b, acc[i], 0, 0, 0);
        }
        __syncthreads();
    }
    const int rowq = (l >> 4) * 4;           // C/D layout: col=lane&15, row=(lane>>4)*4+reg
#pragma unroll
    for (int i = 0; i < 4; ++i)
#pragma unroll
        for (int j = 0; j < 4; ++j) {
            int m = mBase + w * 16 + rowq + j;
            zxb[(size_t)(m - t0) * NGATE + nBase + i * 16 + lm] = f2bf(acc[i][j]);
        }
}

// ---------------- persistent recurrent scan ----------------
// 128 WGs x 256 thr. WG owns units [wg*8, wg*8+8) -> 32 gate columns.
// lane: col32 = lane&31 (column within WG), khalf = lane>>5.
// wave w handles k in [w*256, (w+1)*256); thread k-range = 128, weights in VGPRs.

__global__ __launch_bounds__(256, 1) void scan_kernel(
        const unsigned short* __restrict__ zxb,
        const float* __restrict__ rker,
        const float* __restrict__ bias,
        float* __restrict__ out,
        float* hbuf, float* cst, int* flags, int t0, int t1) {
    const int wg    = blockIdx.x;
    const int tid   = threadIdx.x;
    const int wave  = tid >> 6, lane = tid & 63;
    const int col32 = lane & 31;
    const int khalf = lane >> 5;
    const int kbase = (wave * 2 + khalf) * 128;
    const int gate  = col32 >> 3, uin = col32 & 7;
    const int c     = gate * 1024 + wg * UPW + uin;   // original gate-matrix column

    __shared__ float lds_h[1024];
    __shared__ float lds_part[2][3][32];

    // recurrent weights: 128 fp32 in registers per lane
    float wr[128];
#pragma unroll
    for (int j = 0; j < 128; ++j)
        wr[j] = rker[(size_t)(kbase + j) * NGATE + c];

    float bias_v = bias[c];
    float cstate = 0.f;
    if (wave == 0 && lane < UPW) cstate = cst[wg * UPW + lane];

    for (int t = t0; t < t1; ++t) {
        const int par  = t & 1;         // write parity / LDS partial parity
        const int rpar = (t + 1) & 1;   // read parity for h_{t-1}

        float zxv = 0.f;
        if (wave == 0)  // independent of h: issue before poll so latency overlaps the wait
            zxv = bf2f(zxb[(size_t)(t - t0) * NGATE + wg * 32 + col32]);

        // wait: all WGs completed step t-1 (flag value == completed step count)
        while (true) {
            int f0 = __hip_atomic_load(&flags[lane],      __ATOMIC_RELAXED, __HIP_MEMORY_SCOPE_AGENT);
            int f1 = __hip_atomic_load(&flags[64 + lane], __ATOMIC_RELAXED, __HIP_MEMORY_SCOPE_AGENT);
            if (__all((f0 >= t) && (f1 >= t))) break;
        }
        __builtin_amdgcn_fence(__ATOMIC_ACQUIRE, "agent");

        // stage this wave's 256 h values into LDS (wave-private region; no barrier needed)
        {
            float* hs = hbuf + rpar * 1024 + wave * 256 + lane * 4;
            float h0 = __hip_atomic_load(hs + 0, __ATOMIC_RELAXED, __HIP_MEMORY_SCOPE_AGENT);
            float h1 = __hip_atomic_load(hs + 1, __ATOMIC_RELAXED, __HIP_MEMORY_SCOPE_AGENT);
            float h2 = __hip_atomic_load(hs + 2, __ATOMIC_RELAXED, __HIP_MEMORY_SCOPE_AGENT);
            float h3 = __hip_atomic_load(hs + 3, __ATOMIC_RELAXED, __HIP_MEMORY_SCOPE_AGENT);
            floatx4 hv = {h0, h1, h2, h3};
            *(floatx4*)&lds_h[wave * 256 + lane * 4] = hv;
        }

        // 128 MACs per lane, 4 accumulators to break dep chain; LDS reads are 2-way broadcast
        float z0 = 0.f, z1 = 0.f, z2 = 0.f, z3 = 0.f;
#pragma unroll
        for (int j = 0; j < 32; ++j) {
            floatx4 hv = *(const floatx4*)&lds_h[kbase + j * 4];
            z0 = fmaf(wr[4 * j + 0], hv[0], z0);
            z1 = fmaf(wr[4 * j + 1], hv[1], z1);
            z2 = fmaf(wr[4 * j + 2], hv[2], z2);
            z3 = fmaf(wr[4 * j + 3], hv[3], z3);
        }
        float z = (z0 + z1) + (z2 + z3);
        z += __shfl_down(z, 32);                 // merge khalf partner

        if (wave > 0 && lane < 32) lds_part[par][wave - 1][lane] = z;
        __syncthreads();

        if (wave == 0) {
            if (lane < 32) {
                z += lds_part[par][0][lane] + lds_part[par][1][lane] + lds_part[par][2][lane];
                z += bias_v + zxv;
            }
            int u = lane & 7;
            float g0 = __shfl(z,      u);        // i
            float g1 = __shfl(z,  8 + u);        // f
            float g2 = __shfl(z, 16 + u);        // g
            float g3 = __shfl(z, 24 + u);        // o
            if (lane < UPW) {
                float ig = fast_sigmoid(g0);
                float fg = fast_sigmoid(g1);
                float gg = fast_tanh(g2);
                float og = fast_sigmoid(g3);
                cstate = fg * cstate + ig * gg;
                float h = og * fast_tanh(cstate);
                out[(size_t)t * DIM + wg * UPW + lane] = h;
                __hip_atomic_store(&hbuf[par * 1024 + wg * UPW + lane], h,
                                   __ATOMIC_RELAXED, __HIP_MEMORY_SCOPE_AGENT);
            }
            if (lane == 0)  // release: wave-wide vmcnt drain orders lanes 0-7's h stores
                __hip_atomic_store(&flags[wg], t + 1,
                                   __ATOMIC_RELEASE, __HIP_MEMORY_SCOPE_AGENT);
        }
    }
    if (wave == 0 && lane < UPW) cst[wg * UPW + lane] = cstate;
}

// ---------------- host ----------------

extern "C" void kernel_launch(void* const* d_in, const int* in_sizes, int n_in,
                              void* d_out, int out_size, void* d_ws, size_t ws_size,
                              hipStream_t stream) {
    const float* x    = (const float*)d_in[0];   // [1,T,D]
    const float* kern = (const float*)d_in[1];   // [D,4U]
    const float* rker = (const float*)d_in[2];   // [U,4U]
    const float* bias = (const float*)d_in[3];   // [4U]
    float* out = (float*)d_out;                  // [1,T,U]

    char* ws = (char*)d_ws;
    size_t off = 0;
    auto alloc = [&](size_t bytes) {
        char* p = ws + off;
        off = (off + bytes + 255) & ~(size_t)255;
        return p;
    };
    unsigned short* wbt = (unsigned short*)alloc((size_t)NGATE * DIM * 2);   // 8 MB
    unsigned short* xb  = (unsigned short*)alloc((size_t)T_STEPS * DIM * 2); // 64 MB
    float* hbuf = (float*)alloc(2 * 1024 * 4);
    float* cst  = (float*)alloc(1024 * 4);
    int*   flags = (int*)alloc(GWG * 4);

    // T-chunked zx buffer: adapts to whatever ws_size we actually have
    size_t avail = ws_size > off ? ws_size - off : 0;
    size_t tcmax = avail / ((size_t)NGATE * 2);
    if (tcmax > T_STEPS) tcmax = T_STEPS;
    int TC = (int)(tcmax & ~(size_t)63);
    if (TC < 64) TC = 64;
    unsigned short* zxb = (unsigned short*)alloc((size_t)TC * NGATE * 2);

    hipLaunchKernelGGL(conv_w_kernel, dim3(4096), dim3(256), 0, stream, kern, wbt);
    hipLaunchKernelGGL(conv_x_kernel, dim3((T_STEPS * DIM / 4 + 255) / 256), dim3(256),
                       0, stream, x, xb, (long)(T_STEPS * DIM / 4));
    hipLaunchKernelGGL(init_kernel, dim3(1), dim3(256), 0, stream, hbuf, cst, flags);

    for (int t0 = 0; t0 < T_STEPS; t0 += TC) {
        int tc = (T_STEPS - t0 < TC) ? (T_STEPS - t0) : TC;
        hipLaunchKernelGGL(gemm_kernel, dim3(tc / 64, NGATE / 64), dim3(256),
                           0, stream, xb, wbt, zxb, t0);
        hipLaunchKernelGGL(scan_kernel, dim3(GWG), dim3(256),
                           0, stream, zxb, rker, bias, out, hbuf, cst, flags, t0, t0 + tc);
    }
}

// Round 2
// 155070.520 us; speedup vs baseline: 2.3940x; 2.3940x over previous
//
#include <hip/hip_runtime.h>
#include <hip/hip_bf16.h>

#define T_STEPS 32768
#define DIM     1024    // D == U == 1024
#define NGATE   4096    // 4*U
#define GWG     128     // persistent workgroups in scan
#define UPW     8       // units per WG (1024/128)

typedef __attribute__((ext_vector_type(8))) short  short8;
typedef __attribute__((ext_vector_type(4))) float  floatx4;

static __device__ __forceinline__ unsigned short f2bf(float f) {
    union { __hip_bfloat16 h; unsigned short u; } cv;
    cv.h = __float2bfloat16(f);
    return cv.u;
}
static __device__ __forceinline__ float fast_sigmoid(float x) {
    float e = __builtin_amdgcn_exp2f(x * -1.442695041f);   // exp(-x)
    return __builtin_amdgcn_rcpf(1.f + e);
}
static __device__ __forceinline__ float fast_tanh(float x) {
    float e = __builtin_amdgcn_exp2f(x * -2.885390082f);   // exp(-2x)
    return __builtin_amdgcn_rcpf(1.f + e) * 2.f - 1.f;
}

// ---------------- conversion kernels ----------------

// x fp32 [T*D] -> bf16, 4 elems/thread
__global__ void conv_x_kernel(const float* __restrict__ x,
                              unsigned short* __restrict__ xb, long n4) {
    long i = (long)blockIdx.x * blockDim.x + threadIdx.x;
    if (i >= n4) return;
    floatx4 v = ((const floatx4*)x)[i];
    unsigned long long p =  (unsigned long long)f2bf(v[0])
                         | ((unsigned long long)f2bf(v[1]) << 16)
                         | ((unsigned long long)f2bf(v[2]) << 32)
                         | ((unsigned long long)f2bf(v[3]) << 48);
    ((unsigned long long*)xb)[i] = p;
}

// kernel fp32 [K=1024][4096] -> Wbt bf16 [N=4096][K=1024], with gate/unit remap:
// n(c) groups columns as [wg][gate][unit_in_wg] so each scan WG reads 32 contiguous zx cols.
__global__ void conv_w_kernel(const float* __restrict__ kern,
                              unsigned short* __restrict__ wbt) {
    int idx = blockIdx.x * 256 + threadIdx.x;    // 4096 blocks -> 1M threads
    int kb  = idx >> 12;                         // k block of 4 (0..255)
    int c   = idx & 4095;                        // original column
    int n = ((c & 1023) >> 3) * 32 + (c >> 10) * 8 + (c & 7);
    unsigned long long p = 0;
#pragma unroll
    for (int i = 0; i < 4; ++i) {
        float f = kern[(size_t)(kb * 4 + i) * NGATE + c];
        p |= (unsigned long long)f2bf(f) << (16 * i);
    }
    ((unsigned long long*)(wbt + (size_t)n * DIM))[kb] = p;
}

__global__ void init_kernel(float* hbuf, float* cst, int* flags) {
    int t = threadIdx.x;
    for (int i = t; i < 2048; i += 256) hbuf[i] = 0.f;
    for (int i = t; i < 1024; i += 256) cst[i] = 0.f;
    if (t < GWG) flags[t] = 0;
}

// ---------------- zx GEMM: zxf[t][n'] = sum_k xb[t][k] * Wbt[n'][k]  (bf16 MFMA, fp32 out) ---

__global__ __launch_bounds__(256) void gemm_kernel(
        const unsigned short* __restrict__ xb,
        const unsigned short* __restrict__ wbt,
        float* __restrict__ zxf, int t0) {
    __shared__ unsigned short As[64 * 40];   // 64 rows x 32 k, stride 40 (pad)
    __shared__ unsigned short Bs[64 * 40];
    const int tid = threadIdx.x;
    const int w = tid >> 6, l = tid & 63;
    const int mBase = t0 + blockIdx.x * 64;  // global t row
    const int nBase = blockIdx.y * 64;
    const int r  = tid >> 2;                 // staging row 0..63
    const int kc = (tid & 3) * 8;            // staging k offset
    const int lm = l & 15, kq = l >> 4;

    floatx4 acc[4];
#pragma unroll
    for (int i = 0; i < 4; ++i) acc[i] = (floatx4){0.f, 0.f, 0.f, 0.f};

    for (int kt = 0; kt < DIM; kt += 32) {
        *(uint4*)&As[r * 40 + kc] = *(const uint4*)&xb [(size_t)(mBase + r) * DIM + kt + kc];
        *(uint4*)&Bs[r * 40 + kc] = *(const uint4*)&wbt[(size_t)(nBase + r) * DIM + kt + kc];
        __syncthreads();
        short8 a = *(const short8*)&As[(w * 16 + lm) * 40 + kq * 8];
#pragma unroll
        for (int i = 0; i < 4; ++i) {
            short8 b = *(const short8*)&Bs[(i * 16 + lm) * 40 + kq * 8];
            acc[i] = __builtin_amdgcn_mfma_f32_16x16x32_bf16(a, b, acc[i], 0, 0, 0);
        }
        __syncthreads();
    }
    const int rowq = (l >> 4) * 4;           // C/D layout: col=lane&15, row=(lane>>4)*4+reg
#pragma unroll
    for (int i = 0; i < 4; ++i)
#pragma unroll
        for (int j = 0; j < 4; ++j) {
            int m = mBase + w * 16 + rowq + j;
            zxf[(size_t)(m - t0) * NGATE + nBase + i * 16 + lm] = acc[i][j];
        }
}

// ---------------- persistent recurrent scan ----------------
// 128 WGs x 256 thr. WG owns units [wg*8, wg*8+8) -> 32 gate columns.
// Hand-rolled release/acquire: all h/flag traffic is sc1 (LLC-coherent); NO C++ fences,
// so no per-step buffer_wbl2 / buffer_inv (round-1's 27k-cycle/step killer).

__global__ __launch_bounds__(256, 1) void scan_kernel(
        const float* __restrict__ zxf,
        const float* __restrict__ rker,
        const float* __restrict__ bias,
        float* __restrict__ out,
        float* hbuf, float* cst, int* flags, int t0, int t1) {
    const int wg    = blockIdx.x;
    const int tid   = threadIdx.x;
    const int wave  = tid >> 6, lane = tid & 63;
    const int col32 = lane & 31;
    const int khalf = lane >> 5;
    const int kbase = (wave * 2 + khalf) * 128;
    const int gate  = col32 >> 3, uin = col32 & 7;
    const int c     = gate * 1024 + wg * UPW + uin;   // original gate-matrix column

    __shared__ float lds_h[1024];
    __shared__ float lds_part[2][3][32];

    // recurrent weights: 128 fp32 in registers per lane
    float wr[128];
#pragma unroll
    for (int j = 0; j < 128; ++j)
        wr[j] = rker[(size_t)(kbase + j) * NGATE + c];

    float bias_v = bias[c];
    float cstate = 0.f;
    if (wave == 0 && lane < UPW) cstate = cst[wg * UPW + lane];

    const long long* flp = (const long long*)flags;   // pair-load: flags[2*lane], flags[2*lane+1]

    for (int t = t0; t < t1; ++t) {
        const int par  = t & 1;         // write parity / LDS partial parity
        const int rpar = (t + 1) & 1;   // read parity for h_{t-1}

        float zxv = 0.f;
        if (wave == 0)  // independent of h: issue before poll so latency overlaps the wait
            zxv = zxf[(size_t)(t - t0) * NGATE + wg * 32 + col32];

        // wait: all 128 WGs completed step t-1 (flag value == completed step count)
        while (true) {
            long long f2 = __hip_atomic_load(&flp[lane], __ATOMIC_RELAXED,
                                             __HIP_MEMORY_SCOPE_AGENT);
            int lo = (int)(unsigned int)f2;
            int hi = (int)(f2 >> 32);
            if (__all((lo >= t) && (hi >= t))) break;
        }
        asm volatile("" ::: "memory");   // compiler barrier only; sc1 loads can't be stale

        // stage this wave's 256 h values into LDS (wave-private region; no barrier needed)
        {
            const float* hs = hbuf + rpar * 1024 + wave * 256 + lane * 4;
            floatx4 hv;
            asm volatile("global_load_dwordx4 %0, %1, off sc0 sc1\n\t"
                         "s_waitcnt vmcnt(0)"
                         : "=v"(hv) : "v"(hs) : "memory");
            *(floatx4*)&lds_h[wave * 256 + lane * 4] = hv;
        }

        // 128 MACs per lane, 4 accumulators to break dep chain; LDS reads are 2-way broadcast
        float z0 = 0.f, z1 = 0.f, z2 = 0.f, z3 = 0.f;
#pragma unroll
        for (int j = 0; j < 32; ++j) {
            floatx4 hv = *(const floatx4*)&lds_h[kbase + j * 4];
            z0 = fmaf(wr[4 * j + 0], hv[0], z0);
            z1 = fmaf(wr[4 * j + 1], hv[1], z1);
            z2 = fmaf(wr[4 * j + 2], hv[2], z2);
            z3 = fmaf(wr[4 * j + 3], hv[3], z3);
        }
        float z = (z0 + z1) + (z2 + z3);
        z += __shfl_down(z, 32);                 // merge khalf partner

        if (wave > 0 && lane < 32) lds_part[par][wave - 1][lane] = z;
        __syncthreads();

        if (wave == 0) {
            if (lane < 32) {
                z += lds_part[par][0][lane] + lds_part[par][1][lane] + lds_part[par][2][lane];
                z += bias_v + zxv;
            }
            int u = lane & 7;
            float g0 = __shfl(z,      u);        // i
            float g1 = __shfl(z,  8 + u);        // f
            float g2 = __shfl(z, 16 + u);        // g
            float g3 = __shfl(z, 24 + u);        // o
            if (lane < UPW) {
                float ig = fast_sigmoid(g0);
                float fg = fast_sigmoid(g1);
                float gg = fast_tanh(g2);
                float og = fast_sigmoid(g3);
                cstate = fg * cstate + ig * gg;
                float h = og * fast_tanh(cstate);
                out[(size_t)t * DIM + wg * UPW + lane] = h;
                __hip_atomic_store(&hbuf[par * 1024 + wg * UPW + lane], h,
                                   __ATOMIC_RELAXED, __HIP_MEMORY_SCOPE_AGENT);
            }
            // hand-rolled release: drain this wave's stores (sc1 -> complete at LLC),
            // then publish the flag. No buffer_wbl2.
            asm volatile("s_waitcnt vmcnt(0)" ::: "memory");
            if (lane == 0)
                __hip_atomic_store(&flags[wg], t + 1,
                                   __ATOMIC_RELAXED, __HIP_MEMORY_SCOPE_AGENT);
        }
    }
    if (wave == 0 && lane < UPW) cst[wg * UPW + lane] = cstate;
}

// ---------------- host ----------------

extern "C" void kernel_launch(void* const* d_in, const int* in_sizes, int n_in,
                              void* d_out, int out_size, void* d_ws, size_t ws_size,
                              hipStream_t stream) {
    const float* x    = (const float*)d_in[0];   // [1,T,D]
    const float* kern = (const float*)d_in[1];   // [D,4U]
    const float* rker = (const float*)d_in[2];   // [U,4U]
    const float* bias = (const float*)d_in[3];   // [4U]
    float* out = (float*)d_out;                  // [1,T,U]

    char* ws = (char*)d_ws;
    size_t off = 0;
    auto alloc = [&](size_t bytes) {
        char* p = ws + off;
        off = (off + bytes + 255) & ~(size_t)255;
        return p;
    };
    unsigned short* wbt = (unsigned short*)alloc((size_t)NGATE * DIM * 2);   // 8 MB
    unsigned short* xb  = (unsigned short*)alloc((size_t)T_STEPS * DIM * 2); // 64 MB
    float* hbuf = (float*)alloc(2 * 1024 * 4);
    float* cst  = (float*)alloc(1024 * 4);
    int*   flags = (int*)alloc(GWG * 4);

    // T-chunked fp32 zx buffer: adapts to whatever ws_size we actually have
    size_t avail = ws_size > off ? ws_size - off : 0;
    size_t tcmax = avail / ((size_t)NGATE * 4);
    if (tcmax > T_STEPS) tcmax = T_STEPS;
    int TC = (int)(tcmax & ~(size_t)63);
    if (TC < 64) TC = 64;
    float* zxf = (float*)alloc((size_t)TC * NGATE * 4);

    hipLaunchKernelGGL(conv_w_kernel, dim3(4096), dim3(256), 0, stream, kern, wbt);
    hipLaunchKernelGGL(conv_x_kernel, dim3((T_STEPS * DIM / 4 + 255) / 256), dim3(256),
                       0, stream, x, xb, (long)(T_STEPS * DIM / 4));
    hipLaunchKernelGGL(init_kernel, dim3(1), dim3(256), 0, stream, hbuf, cst, flags);

    for (int t0 = 0; t0 < T_STEPS; t0 += TC) {
        int tc = (T_STEPS - t0 < TC) ? (T_STEPS - t0) : TC;
        hipLaunchKernelGGL(gemm_kernel, dim3(tc / 64, NGATE / 64), dim3(256),
                           0, stream, xb, wbt, zxf, t0);
        hipLaunchKernelGGL(scan_kernel, dim3(GWG), dim3(256),
                           0, stream, zxf, rker, bias, out, hbuf, cst, flags, t0, t0 + tc);
    }
}

// Round 3
// 68207.281 us; speedup vs baseline: 5.4429x; 2.2735x over previous
//
#include <hip/hip_runtime.h>
#include <hip/hip_bf16.h>

#define T_STEPS 32768
#define DIM     1024    // D == U == 1024
#define NGATE   4096    // 4*U
#define GWG     128     // persistent workgroups in scan
#define UPW     8       // units per WG (1024/128)

typedef __attribute__((ext_vector_type(8))) short  short8;
typedef __attribute__((ext_vector_type(4))) float  floatx4;

static __device__ __forceinline__ unsigned short f2bf(float f) {
    union { __hip_bfloat16 h; unsigned short u; } cv;
    cv.h = __float2bfloat16(f);
    return cv.u;
}
static __device__ __forceinline__ float fast_sigmoid(float x) {
    float e = __builtin_amdgcn_exp2f(x * -1.442695041f);   // exp(-x)
    return __builtin_amdgcn_rcpf(1.f + e);
}
static __device__ __forceinline__ float fast_tanh(float x) {
    float e = __builtin_amdgcn_exp2f(x * -2.885390082f);   // exp(-2x)
    return __builtin_amdgcn_rcpf(1.f + e) * 2.f - 1.f;
}

// ---------------- conversion kernels ----------------

// x fp32 [T*D] -> bf16, 4 elems/thread
__global__ void conv_x_kernel(const float* __restrict__ x,
                              unsigned short* __restrict__ xb, long n4) {
    long i = (long)blockIdx.x * blockDim.x + threadIdx.x;
    if (i >= n4) return;
    floatx4 v = ((const floatx4*)x)[i];
    unsigned long long p =  (unsigned long long)f2bf(v[0])
                         | ((unsigned long long)f2bf(v[1]) << 16)
                         | ((unsigned long long)f2bf(v[2]) << 32)
                         | ((unsigned long long)f2bf(v[3]) << 48);
    ((unsigned long long*)xb)[i] = p;
}

// kernel fp32 [K=1024][4096] -> Wbt bf16 [N=4096][K=1024], with gate/unit remap:
// n(c) groups columns as [wg][gate][unit_in_wg] so each scan WG reads 32 contiguous zx cols.
__global__ void conv_w_kernel(const float* __restrict__ kern,
                              unsigned short* __restrict__ wbt) {
    int idx = blockIdx.x * 256 + threadIdx.x;    // 4096 blocks -> 1M threads
    int kb  = idx >> 12;                         // k block of 4 (0..255)
    int c   = idx & 4095;                        // original column
    int n = ((c & 1023) >> 3) * 32 + (c >> 10) * 8 + (c & 7);
    unsigned long long p = 0;
#pragma unroll
    for (int i = 0; i < 4; ++i) {
        float f = kern[(size_t)(kb * 4 + i) * NGATE + c];
        p |= (unsigned long long)f2bf(f) << (16 * i);
    }
    ((unsigned long long*)(wbt + (size_t)n * DIM))[kb] = p;
}

// hbuf8: 2 buffers x 1024 units of (fp32 h, int32 tag). Buffer b=t&1 holds h_t with tag t.
// Step t reads buffer (t+1)&1 expecting tag t-1. Init: buf0 tag -2 (never read), buf1 tag -1.
__global__ void init_kernel(long long* hbuf8, float* cst) {
    int t = threadIdx.x;
    for (int u = t; u < 1024; u += 256) {
        hbuf8[u]        = ((long long)(-2)) << 32;   // h=0.0f, tag=-2
        hbuf8[1024 + u] = ((long long)(-1)) << 32;   // h=0.0f, tag=-1
        cst[u] = 0.f;
    }
}

// ---------------- zx GEMM: zxf[t][n'] = sum_k xb[t][k] * Wbt[n'][k]  (bf16 MFMA, fp32 out) ---

__global__ __launch_bounds__(256) void gemm_kernel(
        const unsigned short* __restrict__ xb,
        const unsigned short* __restrict__ wbt,
        float* __restrict__ zxf, int t0) {
    __shared__ unsigned short As[64 * 40];   // 64 rows x 32 k, stride 40 (pad)
    __shared__ unsigned short Bs[64 * 40];
    const int tid = threadIdx.x;
    const int w = tid >> 6, l = tid & 63;
    const int mBase = t0 + blockIdx.x * 64;  // global t row
    const int nBase = blockIdx.y * 64;
    const int r  = tid >> 2;                 // staging row 0..63
    const int kc = (tid & 3) * 8;            // staging k offset
    const int lm = l & 15, kq = l >> 4;

    floatx4 acc[4];
#pragma unroll
    for (int i = 0; i < 4; ++i) acc[i] = (floatx4){0.f, 0.f, 0.f, 0.f};

    for (int kt = 0; kt < DIM; kt += 32) {
        *(uint4*)&As[r * 40 + kc] = *(const uint4*)&xb [(size_t)(mBase + r) * DIM + kt + kc];
        *(uint4*)&Bs[r * 40 + kc] = *(const uint4*)&wbt[(size_t)(nBase + r) * DIM + kt + kc];
        __syncthreads();
        short8 a = *(const short8*)&As[(w * 16 + lm) * 40 + kq * 8];
#pragma unroll
        for (int i = 0; i < 4; ++i) {
            short8 b = *(const short8*)&Bs[(i * 16 + lm) * 40 + kq * 8];
            acc[i] = __builtin_amdgcn_mfma_f32_16x16x32_bf16(a, b, acc[i], 0, 0, 0);
        }
        __syncthreads();
    }
    const int rowq = (l >> 4) * 4;           // C/D layout: col=lane&15, row=(lane>>4)*4+reg
#pragma unroll
    for (int i = 0; i < 4; ++i)
#pragma unroll
        for (int j = 0; j < 4; ++j) {
            int m = mBase + w * 16 + rowq + j;
            zxf[(size_t)(m - t0) * NGATE + nBase + i * 16 + lm] = acc[i][j];
        }
}

// ---------------- persistent recurrent scan ----------------
// 128 WGs x 256 thr. WG owns units [wg*8, wg*8+8) -> 32 gate columns.
// Synchronization: tag rides WITH the data. h stored as atomic 8B (fp32,h-tag) pairs at LLC
// (sc1). Consumers poll their own 2KB h-slice directly; no separate flags, no release drain,
// no C++ fences (round-1's buffer_wbl2 killer), one LLC hop per step instead of two.

__global__ __launch_bounds__(256, 1) void scan_kernel(
        const float* __restrict__ zxf,
        const float* __restrict__ rker,
        const float* __restrict__ bias,
        float* __restrict__ out,
        long long* hbuf8, float* cst, int t0, int t1) {
    const int wg    = blockIdx.x;
    const int tid   = threadIdx.x;
    const int wave  = tid >> 6, lane = tid & 63;
    const int col32 = lane & 31;
    const int khalf = lane >> 5;
    const int kbase = (wave * 2 + khalf) * 128;
    const int gate  = col32 >> 3, uin = col32 & 7;
    const int c     = gate * 1024 + wg * UPW + uin;   // original gate-matrix column

    __shared__ float lds_h[1024];
    __shared__ float lds_part[2][3][32];

    // recurrent weights: 128 fp32 in registers per lane
    float wr[128];
#pragma unroll
    for (int j = 0; j < 128; ++j)
        wr[j] = rker[(size_t)(kbase + j) * NGATE + c];

    float bias_v = bias[c];
    float cstate = 0.f;
    if (wave == 0 && lane < UPW) cstate = cst[wg * UPW + lane];

    for (int t = t0; t < t1; ++t) {
        const int par  = t & 1;         // buffer written this step / LDS partial parity
        const int rpar = (t + 1) & 1;   // buffer read this step (holds h_{t-1}, tag t-1)
        const int etag = t - 1;

        float zxv = 0.f;
        if (wave == 0)  // independent of h: issue before poll so latency overlaps the wait
            zxv = zxf[(size_t)(t - t0) * NGATE + wg * 32 + col32];

        // poll own slice: lane owns units [wave*256 + lane*4, +4) -> 2 x dwordx4 (4 pairs)
        const long long* hb = hbuf8 + (size_t)rpar * 1024 + wave * 256 + lane * 4;
        int4 p0, p1;
        while (true) {
            asm volatile("global_load_dwordx4 %0, %2, off sc0 sc1\n\t"
                         "global_load_dwordx4 %1, %2, off offset:16 sc0 sc1\n\t"
                         "s_waitcnt vmcnt(0)"
                         : "=v"(p0), "=v"(p1) : "v"(hb) : "memory");
            bool ok = (p0.y == etag) && (p0.w == etag) &&
                      (p1.y == etag) && (p1.w == etag);
            if (__all(ok)) break;
        }

        // stage this wave's 256 h values into LDS (wave-private region; no barrier needed)
        floatx4 hv4;
        hv4[0] = __int_as_float(p0.x);
        hv4[1] = __int_as_float(p0.z);
        hv4[2] = __int_as_float(p1.x);
        hv4[3] = __int_as_float(p1.z);
        *(floatx4*)&lds_h[wave * 256 + lane * 4] = hv4;

        // 128 MACs per lane, 4 accumulators; LDS reads are same-address broadcast (free)
        float z0 = 0.f, z1 = 0.f, z2 = 0.f, z3 = 0.f;
#pragma unroll
        for (int j = 0; j < 32; ++j) {
            floatx4 hv = *(const floatx4*)&lds_h[kbase + j * 4];
            z0 = fmaf(wr[4 * j + 0], hv[0], z0);
            z1 = fmaf(wr[4 * j + 1], hv[1], z1);
            z2 = fmaf(wr[4 * j + 2], hv[2], z2);
            z3 = fmaf(wr[4 * j + 3], hv[3], z3);
        }
        float z = (z0 + z1) + (z2 + z3);
        z += __shfl_down(z, 32);                 // merge khalf partner

        if (wave > 0 && lane < 32) lds_part[par][wave - 1][lane] = z;
        __syncthreads();

        if (wave == 0) {
            if (lane < 32) {
                z += lds_part[par][0][lane] + lds_part[par][1][lane] + lds_part[par][2][lane];
                z += bias_v + zxv;
            }
            int u = lane & 7;
            float g0 = __shfl(z,      u);        // i
            float g1 = __shfl(z,  8 + u);        // f
            float g2 = __shfl(z, 16 + u);        // g
            float g3 = __shfl(z, 24 + u);        // o
            if (lane < UPW) {
                float ig = fast_sigmoid(g0);
                float fg = fast_sigmoid(g1);
                float gg = fast_tanh(g2);
                float og = fast_sigmoid(g3);
                cstate = fg * cstate + ig * gg;
                float h = og * fast_tanh(cstate);
                out[(size_t)t * DIM + wg * UPW + lane] = h;
                // publish (h, tag) as one atomic 8B pair; self-releasing, no drain needed
                int2 pr;
                pr.x = __float_as_int(h);
                pr.y = t;
                long long* dst = hbuf8 + (size_t)par * 1024 + wg * UPW + lane;
                asm volatile("global_store_dwordx2 %0, %1, off sc0 sc1"
                             :: "v"(dst), "v"(pr) : "memory");
            }
        }
    }
    if (wave == 0 && lane < UPW) cst[wg * UPW + lane] = cstate;
}

// ---------------- host ----------------

extern "C" void kernel_launch(void* const* d_in, const int* in_sizes, int n_in,
                              void* d_out, int out_size, void* d_ws, size_t ws_size,
                              hipStream_t stream) {
    const float* x    = (const float*)d_in[0];   // [1,T,D]
    const float* kern = (const float*)d_in[1];   // [D,4U]
    const float* rker = (const float*)d_in[2];   // [U,4U]
    const float* bias = (const float*)d_in[3];   // [4U]
    float* out = (float*)d_out;                  // [1,T,U]

    char* ws = (char*)d_ws;
    size_t off = 0;
    auto alloc = [&](size_t bytes) {
        char* p = ws + off;
        off = (off + bytes + 255) & ~(size_t)255;
        return p;
    };
    unsigned short* wbt = (unsigned short*)alloc((size_t)NGATE * DIM * 2);   // 8 MB
    unsigned short* xb  = (unsigned short*)alloc((size_t)T_STEPS * DIM * 2); // 64 MB
    long long* hbuf8 = (long long*)alloc(2 * 1024 * 8);                      // (h, tag) pairs
    float*     cst   = (float*)alloc(1024 * 4);

    // T-chunked fp32 zx buffer: adapts to whatever ws_size we actually have
    size_t avail = ws_size > off ? ws_size - off : 0;
    size_t tcmax = avail / ((size_t)NGATE * 4);
    if (tcmax > T_STEPS) tcmax = T_STEPS;
    int TC = (int)(tcmax & ~(size_t)63);
    if (TC < 64) TC = 64;
    float* zxf = (float*)alloc((size_t)TC * NGATE * 4);

    hipLaunchKernelGGL(conv_w_kernel, dim3(4096), dim3(256), 0, stream, kern, wbt);
    hipLaunchKernelGGL(conv_x_kernel, dim3((T_STEPS * DIM / 4 + 255) / 256), dim3(256),
                       0, stream, x, xb, (long)(T_STEPS * DIM / 4));
    hipLaunchKernelGGL(init_kernel, dim3(1), dim3(256), 0, stream, hbuf8, cst);

    for (int t0 = 0; t0 < T_STEPS; t0 += TC) {
        int tc = (T_STEPS - t0 < TC) ? (T_STEPS - t0) : TC;
        hipLaunchKernelGGL(gemm_kernel, dim3(tc / 64, NGATE / 64), dim3(256),
                           0, stream, xb, wbt, zxf, t0);
        hipLaunchKernelGGL(scan_kernel, dim3(GWG), dim3(256),
                           0, stream, zxf, rker, bias, out, hbuf8, cst, t0, t0 + tc);
    }
}